// Round 4
// baseline (1705.447 us; speedup 1.0000x reference)
//
#include <hip/hip_runtime.h>

// SNN recurrence, B=64 T=256 F=1024 fp32. 256 persistent WGs (1/CU):
// js = bid>>2 (16 output cols), bg = bid&3 (16 batch rows; each XCD hosts
// exactly one bg's WGs). W column-slice lives in REGISTERS as 4 signed
// base-512 digit limbs (exact in bf16); spk@W.T = 4 bf16 MFMAs per K-chunk
// with EXACT integer fp32 accumulation; limbs recombine in fp64; syn/mem fp64.
//
// Fence-free tagged-word exchange: word = ((t+1)<<16)|16 spike bits, relaxed
// agent-scope stores/loads. Bitmap layout puts each consumer lane's 4 A-frag
// words contiguous, so the poll loads ARE the MFMA input. One barrier per
// step: partD WAR (reads at t vs writes at t+1) is protected by the publish
// gate — a wave can only see tag t+1 from its OWN WG (extra gate word, rows
// 0..3) after all 4 ballot-waves published step t, which data-depends on
// their partD reads. 4-deep slot ring (64KB ws), memset per launch.

#define NT 512

typedef __bf16 bf16x8 __attribute__((ext_vector_type(8)));
typedef float f32x4 __attribute__((ext_vector_type(4)));
typedef int i32x4 __attribute__((ext_vector_type(4)));

static __device__ __forceinline__ unsigned short f2bf(float v) {
    union { float f; unsigned int u; } a; a.f = v;
    unsigned int u = a.u;
    u += 0x7fffu + ((u >> 16) & 1u);   // RNE (exact for small ints)
    return (unsigned short)(u >> 16);
}

// 4 signed base-512 digits of round(w * 2^36); digits in [-256,255], exact in bf16.
static __device__ __forceinline__ void decomp512(float w, int* d) {
    long long v = llround((double)w * 68719476736.0);  // 2^36
    #pragma unroll
    for (int i = 0; i < 4; ++i) {
        int r = (int)(v & 511);
        if (r >= 256) r -= 512;
        d[i] = r;
        v = (v - (long long)r) >> 9;
    }
}

__launch_bounds__(NT, 1)
__global__ void snn_persist_kernel(const float* __restrict__ x,
                                   const float* __restrict__ W,
                                   const float* __restrict__ bias,
                                   float* __restrict__ out,
                                   unsigned int* __restrict__ gbm)
{
    constexpr int T = 256, F = 1024;
    const int bid = blockIdx.x;
    const int bg  = bid & 3;    // batch group: rows bg*16..+15 (XCD-local)
    const int js  = bid >> 2;   // j-slice: cols js*16..+15
    const int tid = threadIdx.x;
    const int lane = tid & 63;
    const int wv   = tid >> 6;  // wave 0..7 (K-split: chunks wv*4..wv*4+3)
    const int q = lane >> 4, r15 = lane & 15;
    const int qh = q >> 1, ql = q & 1;

    __shared__ double partD[8*256];    // per-wave limb-recombined partial h
    __shared__ double lds_pad[9216];   // 72KB pad: total 88KB > 80KB -> 1 WG/CU

    if (bias[0] > 1.0e30f) lds_pad[tid] = 1.0;  // never true; keeps pad live

    // ---- W B-frags in registers: wreg[c4][limb], chunk kc = wv*4+c4.
    // Lane supplies B[k=q*8+i][n=r15] = W[js*16+r15][kc*32+q*8+i].
    bf16x8 wreg[4][4];
    #pragma unroll
    for (int c4 = 0; c4 < 4; ++c4) {
        const int kc = wv*4 + c4;
        const float* wr = W + (size_t)(js*16 + r15)*F + kc*32 + q*8;
        float e[8];
        *(float4*)&e[0] = *(const float4*)wr;
        *(float4*)&e[4] = *(const float4*)(wr + 4);
        unsigned int pk[4][4];
        #pragma unroll
        for (int i = 0; i < 4; ++i) {
            int da[4], db[4];
            decomp512(e[2*i],   da);
            decomp512(e[2*i+1], db);
            #pragma unroll
            for (int l = 0; l < 4; ++l)
                pk[l][i] = (unsigned int)f2bf((float)da[l])
                         | ((unsigned int)f2bf((float)db[l]) << 16);
        }
        #pragma unroll
        for (int l = 0; l < 4; ++l) {
            i32x4 t4 = {(int)pk[l][0], (int)pk[l][1], (int)pk[l][2], (int)pk[l][3]};
            wreg[c4][l] = __builtin_bit_cast(bf16x8, t4);
        }
    }

    // state mapping (tid<256), matching MFMA C layout after the LDS reduce:
    // row b = ((tid>>4)&3)*4 + (tid>>6), col j = tid&15
    const int brow = ((tid >> 4) & 3)*4 + (tid >> 6);
    const int jcol = tid & 15;
    const int bglob = bg*16 + brow;
    const double bj = (double)bias[js*16 + jcol];
    const size_t obase = (size_t)bglob*T*F + js*16 + jcol;
    float* outspk = out;
    float* outmem = out + (size_t)64*T*F;

    double syn = 0.0, mem = 0.0, rst = 0.0;
    float xv = (tid < 256) ? x[obase] : 0.f;

    // own-WG gate word (rows 0..3 = ballot waves 0..3, g=0 words)
    const int gown = (js>>3)*128 + (js&1)*64 + (lane&3)*4 + ((js>>1)&3);

    for (int t = 0; t < T; ++t) {
        double h = 0.0;
        if (t > 0) {
            // poll: 4 contiguous A-frag words + 1 own-WG gate word (relaxed sc1)
            const unsigned int tg = (unsigned int)t;   // tag of step t-1 data
            const unsigned int* slot = gbm + (size_t)(((t-1)&3)*4 + bg)*1024;
            const unsigned int* pd = slot + wv*128 + qh*64 + r15*4;
            const unsigned int* pg = slot + gown;
            unsigned int w0, w1, w2, w3, g0;
            do {
                w0 = __hip_atomic_load(pd+0, __ATOMIC_RELAXED, __HIP_MEMORY_SCOPE_AGENT);
                w1 = __hip_atomic_load(pd+1, __ATOMIC_RELAXED, __HIP_MEMORY_SCOPE_AGENT);
                w2 = __hip_atomic_load(pd+2, __ATOMIC_RELAXED, __HIP_MEMORY_SCOPE_AGENT);
                w3 = __hip_atomic_load(pd+3, __ATOMIC_RELAXED, __HIP_MEMORY_SCOPE_AGENT);
                g0 = __hip_atomic_load(pg,   __ATOMIC_RELAXED, __HIP_MEMORY_SCOPE_AGENT);
            } while (__any(((w0>>16)!=tg) | ((w1>>16)!=tg) | ((w2>>16)!=tg) |
                           ((w3>>16)!=tg) | ((g0>>16)!=tg)));

            // MFMA: 4 K-chunks x 4 limbs, exact integer fp32 accumulation
            f32x4 ac0 = {0.f,0.f,0.f,0.f}, ac1 = ac0, ac2 = ac0, ac3 = ac0;
            unsigned int ww[4] = {w0, w1, w2, w3};
            #pragma unroll
            for (int c4 = 0; c4 < 4; ++c4) {
                unsigned int byt = (ww[c4] >> (ql*8)) & 0xFFu;
                unsigned int d0 = ((byt&1u)  ?0x3F80u:0u) | ((byt&2u)  ?0x3F800000u:0u);
                unsigned int d1 = ((byt&4u)  ?0x3F80u:0u) | ((byt&8u)  ?0x3F800000u:0u);
                unsigned int d2 = ((byt&16u) ?0x3F80u:0u) | ((byt&32u) ?0x3F800000u:0u);
                unsigned int d3 = ((byt&64u) ?0x3F80u:0u) | ((byt&128u)?0x3F800000u:0u);
                i32x4 ai = {(int)d0, (int)d1, (int)d2, (int)d3};
                bf16x8 a = __builtin_bit_cast(bf16x8, ai);
                ac0 = __builtin_amdgcn_mfma_f32_16x16x32_bf16(a, wreg[c4][0], ac0, 0,0,0);
                ac1 = __builtin_amdgcn_mfma_f32_16x16x32_bf16(a, wreg[c4][1], ac1, 0,0,0);
                ac2 = __builtin_amdgcn_mfma_f32_16x16x32_bf16(a, wreg[c4][2], ac2, 0,0,0);
                ac3 = __builtin_amdgcn_mfma_f32_16x16x32_bf16(a, wreg[c4][3], ac3, 0,0,0);
            }
            // limb recombine in fp64 (exact): weight of limb i = 2^(9i-36)
            const double c0 = 1.0/68719476736.0, c1 = 1.0/134217728.0;
            const double c2 = 1.0/262144.0,      c3 = 1.0/512.0;
            #pragma unroll
            for (int r = 0; r < 4; ++r)
                partD[wv*256 + r*64 + lane] =
                    (double)ac0[r]*c0 + (double)ac1[r]*c1 +
                    (double)ac2[r]*c2 + (double)ac3[r]*c3;
            __syncthreads();   // the ONE barrier: partD writes(t) before reads(t)
            if (tid < 256) {
                #pragma unroll
                for (int w = 0; w < 8; ++w) h += partD[w*256 + tid];
            }
        }

        // prefetch next x (post-barrier: drains at NEXT step's barrier, off path)
        float xn = 0.f;
        if (tid < 256 && t + 1 < T) xn = x[obase + (size_t)(t+1)*F];

        if (tid < 256) {
            syn = 0.8*syn + (double)xv + h + bj;
            mem = 0.9*mem + syn - rst;
            bool sp = (mem > 1.0);
            unsigned long long m = __ballot(sp);
            // publish FIRST (critical path): wave wv owns rows 4g+wv, g=lane>>4
            if ((lane & 15) == 0) {
                int g = lane >> 4;
                int row = 4*g + wv;
                unsigned int word = (unsigned int)((m >> (16*g)) & 0xFFFFull);
                unsigned int val = (((unsigned int)(t + 1)) << 16) | word;
                unsigned int* dst = gbm + (size_t)((t&3)*4 + bg)*1024
                                  + (js>>3)*128 + (js&1)*64 + row*4 + ((js>>1)&3);
                __hip_atomic_store(dst, val, __ATOMIC_RELAXED, __HIP_MEMORY_SCOPE_AGENT);
            }
            rst = sp ? 1.0 : 0.0;
            outspk[obase + (size_t)t*F] = sp ? 1.0f : 0.0f;
            outmem[obase + (size_t)t*F] = (float)mem;
        }
        xv = xn;
    }
}

extern "C" void kernel_launch(void* const* d_in, const int* in_sizes, int n_in,
                              void* d_out, int out_size, void* d_ws, size_t ws_size,
                              hipStream_t stream) {
    const float* x    = (const float*)d_in[0];
    const float* W    = (const float*)d_in[1];
    const float* bias = (const float*)d_in[2];
    float* out = (float*)d_out;

    // ws: 4-slot ring of tagged bitmaps [slot 0..3][bg 0..3][1024 uints] = 64KB
    unsigned int* gbm = (unsigned int*)d_ws;

    hipMemsetAsync(d_ws, 0, 65536, stream);  // clear tags every launch (replay-safe)
    hipLaunchKernelGGL(snn_persist_kernel, dim3(256), dim3(512), 0, stream,
                       x, W, bias, out, gbm);
}